// Round 1
// baseline (320.182 us; speedup 1.0000x reference)
//
#include <hip/hip_runtime.h>
#include <stdint.h>

#define Bn 4
#define Sn 2048
#define Dn 1024
#define Hn 16
#define HDn 64

typedef unsigned short u16;
typedef unsigned int u32;
typedef __attribute__((ext_vector_type(8))) __bf16 bf16x8;
typedef __attribute__((ext_vector_type(4))) float f32x4;

__device__ __forceinline__ u16 f2bf(float f) {
  union { float f; u32 u; } x; x.f = f;
  u32 r = x.u + 0x7FFFu + ((x.u >> 16) & 1u);   // RNE
  return (u16)(r >> 16);
}

// global -> LDS direct copy, 16B per lane. LDS dest = wave-uniform base + lane*16.
__device__ __forceinline__ void gload16(const u16* g, u16* l) {
  __builtin_amdgcn_global_load_lds(
      (const __attribute__((address_space(1))) void*)g,
      (__attribute__((address_space(3))) void*)l, 16, 0, 0);
}

__global__ void cvt_kernel(const float* __restrict__ in, u16* __restrict__ out, int n4) {
  int i = blockIdx.x * 256 + threadIdx.x;
  if (i < n4) {
    float4 v = ((const float4*)in)[i];
    ushort4 o;
    o.x = f2bf(v.x); o.y = f2bf(v.y); o.z = f2bf(v.z); o.w = f2bf(v.w);
    ((ushort4*)out)[i] = o;
  }
}

// C[M=8192, N=1024] = A[M,K=1024] @ W[N,K]^T + bias, bf16 inputs, fp32 accum.
// MODE 0: write qh bf16 [B,H,S,HD]
// MODE 1: write kh fp32 [B,H,S,HD] (d_out) + kh bf16 [B,H,S,HD] (ws)
// MODE 2: write vh fp32 [B,H,S,HD] (d_out) + v^T bf16 [B,H,HD,S] (ws)
// MODE 3: write out fp32 [M,N] (d_out)
template<int MODE>
__global__ __launch_bounds__(256, 2) void gemm_bt(
    const u16* __restrict__ A, const u16* __restrict__ W,
    const float* __restrict__ bias,
    float* __restrict__ outF, u16* __restrict__ outB)
{
  __shared__ u16 As[2][4096];  // [128][32] bf16, chunk-XOR swizzled
  __shared__ u16 Bs[2][4096];

  const int t = threadIdx.x, w = t >> 6, lane = t & 63;
  int bid = (int)blockIdx.x;
  bid = (bid & 7) * 64 + (bid >> 3);          // bijective XCD swizzle (512 % 8 == 0)
  const int m0 = (bid >> 3) * 128, n0 = (bid & 7) * 128;
  const int wm = (w >> 1) * 64, wn = (w & 1) * 64;
  const int lrow = lane & 15, lko = (lane >> 4) * 8;

  f32x4 acc[4][4] = {};

  auto stage = [&](int buf, int k0) {
    #pragma unroll
    for (int i = 0; i < 2; ++i) {
      const int c = i * 256 + t;
      const int row = c >> 2;
      const int off = ((c & 3) ^ (row & 3)) * 8;   // inverse-swizzled source (rule 21)
      gload16(A + (size_t)(m0 + row) * 1024 + k0 + off, &As[buf][(c & ~63) * 8]);
      gload16(W + (size_t)(n0 + row) * 1024 + k0 + off, &Bs[buf][(c & ~63) * 8]);
    }
  };

  stage(0, 0);
  for (int kt = 0; kt < 32; ++kt) {
    const int buf = kt & 1;
    if (kt < 31) stage(buf ^ 1, (kt + 1) * 32);
    __syncthreads();
    bf16x8 a[4], b[4];
    #pragma unroll
    for (int i = 0; i < 4; ++i) {
      const int ra = wm + i * 16 + lrow;
      const int rb = wn + i * 16 + lrow;
      a[i] = *(const bf16x8*)&As[buf][ra * 32 + (((lane >> 4) ^ (ra & 3)) * 8)];
      b[i] = *(const bf16x8*)&Bs[buf][rb * 32 + (((lane >> 4) ^ (rb & 3)) * 8)];
    }
    #pragma unroll
    for (int i = 0; i < 4; ++i)
      #pragma unroll
      for (int j = 0; j < 4; ++j)
        acc[i][j] = __builtin_amdgcn_mfma_f32_16x16x32_bf16(a[i], b[j], acc[i][j], 0, 0, 0);
    __syncthreads();
  }

  const int g4 = (lane >> 4) * 4;
  #pragma unroll
  for (int i = 0; i < 4; ++i) {
    #pragma unroll
    for (int j = 0; j < 4; ++j) {
      const int gn = n0 + wn + j * 16 + lrow;
      const float bv = bias[gn];
      #pragma unroll
      for (int r = 0; r < 4; ++r) {
        const int gm = m0 + wm + i * 16 + g4 + r;
        const float x = acc[i][j][r] + bv;
        if (MODE == 3) {
          outF[(size_t)gm * 1024 + gn] = x;
        } else {
          const int b_ = gm >> 11, s_ = gm & 2047, h_ = gn >> 6, d_ = gn & 63;
          const size_t hidx = (((size_t)b_ * Hn + h_) * Sn + s_) * HDn + d_;
          if (MODE == 0) outB[hidx] = f2bf(x);
          if (MODE == 1) { outF[hidx] = x; outB[hidx] = f2bf(x); }
          if (MODE == 2) { outF[hidx] = x;
                           outB[(((size_t)b_ * Hn + h_) * HDn + d_) * Sn + s_] = f2bf(x); }
        }
      }
    }
  }
}

// Causal flash attention. Block = (b,h, 64 q-rows); 4 waves x 16 q-rows each.
// qh,kh: [B,H,S,HD] bf16. vt: [B,H,HD,S] bf16 (pre-transposed). ao: [B,S,D] bf16.
__global__ __launch_bounds__(256, 2) void attn_kernel(
    const u16* __restrict__ qh, const u16* __restrict__ kh,
    const u16* __restrict__ vt, u16* __restrict__ ao)
{
  __shared__ u16 Ks[2][4096];     // [64 kv][64 hd], chunk-XOR swizzled
  __shared__ u16 Vs[2][4096];     // [64 d][64 kv], chunk-XOR swizzled
  __shared__ u16 Ps[4][16 * 72];  // per-wave P, +8 pad

  const int t = threadIdx.x, w = t >> 6, lane = t & 63;
  int bid = (int)blockIdx.x;
  bid = (bid & 7) * 256 + (bid >> 3);         // XCD swizzle (2048 % 8 == 0)
  const int qt = bid & 31, bh = bid >> 5;
  const int q0 = qt * 64, qw = q0 + w * 16;
  const int lrow = lane & 15, lko = (lane >> 4) * 8, g4 = (lane >> 4) * 4;

  const u16* Kb = kh + (size_t)bh * Sn * HDn;
  const u16* Vb = vt + (size_t)bh * HDn * Sn;
  const u16* Qb = qh + (size_t)bh * Sn * HDn + (size_t)qw * HDn;

  bf16x8 qa[2];
  qa[0] = *(const bf16x8*)(Qb + lrow * HDn + lko);
  qa[1] = *(const bf16x8*)(Qb + lrow * HDn + 32 + lko);

  float m_r[4], l_r[4];
  f32x4 accO[4] = {};
  #pragma unroll
  for (int r = 0; r < 4; ++r) { m_r[r] = -1e30f; l_r[r] = 0.f; }

  const int NT = qt + 1;

  auto stageKV = [&](int buf, int j0) {
    #pragma unroll
    for (int i = 0; i < 2; ++i) {
      const int c = i * 256 + t;
      const int row = c >> 3;
      const int off = (c & 7) ^ (row & 7);     // inverse-swizzled source
      gload16(Kb + (size_t)(j0 + row) * HDn + off * 8, &Ks[buf][(c & ~63) * 8]);
      gload16(Vb + (size_t)row * Sn + j0 + off * 8, &Vs[buf][(c & ~63) * 8]);
    }
  };

  stageKV(0, 0);
  for (int jt = 0; jt < NT; ++jt) {
    const int buf = jt & 1;
    if (jt + 1 < NT) stageKV(buf ^ 1, (jt + 1) * 64);
    __syncthreads();

    // S = Q K^T  (D[q][kv]; 4 kv-subtiles x 2 k-steps)
    f32x4 sc[4] = {};
    #pragma unroll
    for (int ks = 0; ks < 2; ++ks) {
      #pragma unroll
      for (int n = 0; n < 4; ++n) {
        const int row = n * 16 + lrow;
        const int ch = (ks * 4 + (lane >> 4)) ^ (row & 7);
        bf16x8 kb = *(const bf16x8*)&Ks[buf][row * 64 + ch * 8];
        sc[n] = __builtin_amdgcn_mfma_f32_16x16x32_bf16(qa[ks], kb, sc[n], 0, 0, 0);
      }
    }

    float p[4][4];
    const bool lastT = (jt == NT - 1);
    const int j0 = jt * 64;
    #pragma unroll
    for (int n = 0; n < 4; ++n) {
      #pragma unroll
      for (int r = 0; r < 4; ++r) {
        float x = sc[n][r] * 0.125f;           // 1/sqrt(HD)
        if (lastT && (j0 + n * 16 + lrow) > (qw + g4 + r)) x -= 100000.0f;
        p[n][r] = x;
      }
    }

    // online softmax (rows live across lanes 16g..16g+15)
    #pragma unroll
    for (int r = 0; r < 4; ++r) {
      float mx = fmaxf(fmaxf(p[0][r], p[1][r]), fmaxf(p[2][r], p[3][r]));
      #pragma unroll
      for (int o = 1; o < 16; o <<= 1) mx = fmaxf(mx, __shfl_xor(mx, o, 64));
      const float mn = fmaxf(m_r[r], mx);
      const float al = __expf(m_r[r] - mn);
      m_r[r] = mn;
      float sum = 0.f;
      #pragma unroll
      for (int n = 0; n < 4; ++n) { p[n][r] = __expf(p[n][r] - mn); sum += p[n][r]; }
      #pragma unroll
      for (int o = 1; o < 16; o <<= 1) sum += __shfl_xor(sum, o, 64);
      l_r[r] = l_r[r] * al + sum;
      #pragma unroll
      for (int n = 0; n < 4; ++n) accO[n][r] *= al;
    }

    // P -> LDS (bf16, padded row stride 72) for A-operand re-layout
    u16* pb = &Ps[w][0];
    #pragma unroll
    for (int n = 0; n < 4; ++n)
      #pragma unroll
      for (int r = 0; r < 4; ++r)
        pb[(g4 + r) * 72 + n * 16 + lrow] = f2bf(p[n][r]);

    asm volatile("s_waitcnt lgkmcnt(0)" ::: "memory");
    __builtin_amdgcn_sched_barrier(0);

    // O += P V  (B-operand from transposed V tile)
    #pragma unroll
    for (int ks = 0; ks < 2; ++ks) {
      bf16x8 pa = *(const bf16x8*)&pb[lrow * 72 + ks * 32 + lko];
      #pragma unroll
      for (int n = 0; n < 4; ++n) {
        const int row = n * 16 + lrow;
        const int ch = (ks * 4 + (lane >> 4)) ^ (row & 7);
        bf16x8 vb = *(const bf16x8*)&Vs[buf][row * 64 + ch * 8];
        accO[n] = __builtin_amdgcn_mfma_f32_16x16x32_bf16(pa, vb, accO[n], 0, 0, 0);
      }
    }
    __syncthreads();
  }

  const int b_ = bh >> 4, h_ = bh & 15;
  #pragma unroll
  for (int n = 0; n < 4; ++n)
    #pragma unroll
    for (int r = 0; r < 4; ++r) {
      const float x = accO[n][r] / l_r[r];
      const int qrow = qw + g4 + r;
      ao[((size_t)b_ * Sn + qrow) * Dn + h_ * HDn + n * 16 + lrow] = f2bf(x);
    }
}

extern "C" void kernel_launch(void* const* d_in, const int* in_sizes, int n_in,
                              void* d_out, int out_size, void* d_ws, size_t ws_size,
                              hipStream_t stream)
{
  const float* q  = (const float*)d_in[0];
  const float* k  = (const float*)d_in[1];
  const float* v  = (const float*)d_in[2];
  // d_in[3] = mask: fixed causal triu -> implemented analytically, never read
  const float* Wq = (const float*)d_in[4];
  const float* bq = (const float*)d_in[5];
  const float* Wk = (const float*)d_in[6];
  const float* bk = (const float*)d_in[7];
  const float* Wv = (const float*)d_in[8];
  const float* bv = (const float*)d_in[9];
  const float* Wo = (const float*)d_in[10];
  const float* bo = (const float*)d_in[11];

  float* out_o  = (float*)d_out;                       // [B,S,D]
  float* out_kh = out_o + (size_t)Bn * Sn * Dn;        // [B,H,S,HD]
  float* out_vh = out_kh + (size_t)Bn * Sn * Dn;       // [B,H,S,HD]

  char* ws = (char*)d_ws;
  const size_t MB = 1ull << 20;
  u16* wq_bf = (u16*)(ws + 0 * MB);
  u16* wk_bf = (u16*)(ws + 2 * MB);
  u16* wv_bf = (u16*)(ws + 4 * MB);
  u16* wo_bf = (u16*)(ws + 6 * MB);
  u16* q_bf  = (u16*)(ws + 8 * MB);     // [8192,1024] bf16
  u16* k_bf  = (u16*)(ws + 24 * MB);
  u16* v_bf  = (u16*)(ws + 40 * MB);
  u16* qh_bf = (u16*)(ws + 56 * MB);    // [B,H,S,HD]
  u16* kh_bf = (u16*)(ws + 72 * MB);    // [B,H,S,HD]
  u16* vt_bf = (u16*)(ws + 88 * MB);    // [B,H,HD,S]
  u16* ao_bf = q_bf;                    // alias: q_bf dead after GEMM Q

  const int NC = Bn * Sn * Dn / 4;      // 2,097,152 float4s
  cvt_kernel<<<NC / 256, 256, 0, stream>>>(q, q_bf, NC);
  cvt_kernel<<<NC / 256, 256, 0, stream>>>(k, k_bf, NC);
  cvt_kernel<<<NC / 256, 256, 0, stream>>>(v, v_bf, NC);
  const int NW = Dn * Dn / 4;           // 262,144
  cvt_kernel<<<NW / 256, 256, 0, stream>>>(Wq, wq_bf, NW);
  cvt_kernel<<<NW / 256, 256, 0, stream>>>(Wk, wk_bf, NW);
  cvt_kernel<<<NW / 256, 256, 0, stream>>>(Wv, wv_bf, NW);
  cvt_kernel<<<NW / 256, 256, 0, stream>>>(Wo, wo_bf, NW);

  gemm_bt<0><<<512, 256, 0, stream>>>(q_bf, wq_bf, bq, nullptr, qh_bf);
  gemm_bt<1><<<512, 256, 0, stream>>>(k_bf, wk_bf, bk, out_kh, kh_bf);
  gemm_bt<2><<<512, 256, 0, stream>>>(v_bf, wv_bf, bv, out_vh, vt_bf);

  attn_kernel<<<2048, 256, 0, stream>>>(qh_bf, kh_bf, vt_bf, ao_bf);

  gemm_bt<3><<<512, 256, 0, stream>>>(ao_bf, wo_bf, bo, out_o, nullptr);
}

// Round 2
// 245.659 us; speedup vs baseline: 1.3034x; 1.3034x over previous
//
#include <hip/hip_runtime.h>
#include <stdint.h>

#define Bn 4
#define Sn 2048
#define Dn 1024
#define Hn 16
#define HDn 64

typedef unsigned short u16;
typedef unsigned int u32;
typedef __attribute__((ext_vector_type(8))) __bf16 bf16x8;
typedef __attribute__((ext_vector_type(4))) float f32x4;

__device__ __forceinline__ u16 f2bf(float f) {
  union { float f; u32 u; } x; x.f = f;
  u32 r = x.u + 0x7FFFu + ((x.u >> 16) & 1u);   // RNE
  return (u16)(r >> 16);
}

// global -> LDS direct copy, 16B per lane. LDS dest = wave-uniform base + lane*16.
__device__ __forceinline__ void gload16(const u16* g, u16* l) {
  __builtin_amdgcn_global_load_lds(
      (const __attribute__((address_space(1))) void*)g,
      (__attribute__((address_space(3))) void*)l, 16, 0, 0);
}

__global__ void cvt_kernel(const float* __restrict__ in, u16* __restrict__ out, int n4) {
  int i = blockIdx.x * 256 + threadIdx.x;
  if (i < n4) {
    float4 v = ((const float4*)in)[i];
    ushort4 o;
    o.x = f2bf(v.x); o.y = f2bf(v.y); o.z = f2bf(v.z); o.w = f2bf(v.w);
    ((ushort4*)out)[i] = o;
  }
}

// C[M=8192, N=1024] = A[M,K=1024] @ W[N,K]^T + bias, bf16 inputs, fp32 accum.
template<int MODE>
__global__ __launch_bounds__(256, 2) void gemm_bt(
    const u16* __restrict__ A, const u16* __restrict__ W,
    const float* __restrict__ bias,
    float* __restrict__ outF, u16* __restrict__ outB)
{
  __shared__ u16 As[2][4096];  // [128][32] bf16, chunk-XOR swizzled
  __shared__ u16 Bs[2][4096];

  const int t = threadIdx.x, w = t >> 6, lane = t & 63;
  int bid = (int)blockIdx.x;
  bid = (bid & 7) * 64 + (bid >> 3);          // bijective XCD swizzle (512 % 8 == 0)
  const int m0 = (bid >> 3) * 128, n0 = (bid & 7) * 128;
  const int wm = (w >> 1) * 64, wn = (w & 1) * 64;
  const int lrow = lane & 15;

  f32x4 acc[4][4] = {};

  auto stage = [&](int buf, int k0) {
    #pragma unroll
    for (int i = 0; i < 2; ++i) {
      const int c = i * 256 + t;
      const int row = c >> 2;
      const int off = ((c & 3) ^ (row & 3)) * 8;   // inverse-swizzled source
      gload16(A + (size_t)(m0 + row) * 1024 + k0 + off, &As[buf][(c & ~63) * 8]);
      gload16(W + (size_t)(n0 + row) * 1024 + k0 + off, &Bs[buf][(c & ~63) * 8]);
    }
  };

  stage(0, 0);
  for (int kt = 0; kt < 32; ++kt) {
    const int buf = kt & 1;
    if (kt < 31) stage(buf ^ 1, (kt + 1) * 32);
    __syncthreads();
    bf16x8 a[4], b[4];
    #pragma unroll
    for (int i = 0; i < 4; ++i) {
      const int ra = wm + i * 16 + lrow;
      const int rb = wn + i * 16 + lrow;
      a[i] = *(const bf16x8*)&As[buf][ra * 32 + (((lane >> 4) ^ (ra & 3)) * 8)];
      b[i] = *(const bf16x8*)&Bs[buf][rb * 32 + (((lane >> 4) ^ (rb & 3)) * 8)];
    }
    #pragma unroll
    for (int i = 0; i < 4; ++i)
      #pragma unroll
      for (int j = 0; j < 4; ++j)
        acc[i][j] = __builtin_amdgcn_mfma_f32_16x16x32_bf16(a[i], b[j], acc[i][j], 0, 0, 0);
    __syncthreads();
  }

  const int g4 = (lane >> 4) * 4;
  #pragma unroll
  for (int i = 0; i < 4; ++i) {
    #pragma unroll
    for (int j = 0; j < 4; ++j) {
      const int gn = n0 + wn + j * 16 + lrow;
      const float bv = bias[gn];
      #pragma unroll
      for (int r = 0; r < 4; ++r) {
        const int gm = m0 + wm + i * 16 + g4 + r;
        const float x = acc[i][j][r] + bv;
        if (MODE == 3) {
          outF[(size_t)gm * 1024 + gn] = x;
        } else {
          const int b_ = gm >> 11, s_ = gm & 2047, h_ = gn >> 6, d_ = gn & 63;
          const size_t hidx = (((size_t)b_ * Hn + h_) * Sn + s_) * HDn + d_;
          if (MODE == 0) outB[hidx] = f2bf(x);
          if (MODE == 1) { outF[hidx] = x; outB[hidx] = f2bf(x); }
          if (MODE == 2) { outF[hidx] = x;
                           outB[(((size_t)b_ * Hn + h_) * HDn + d_) * Sn + s_] = f2bf(x); }
        }
      }
    }
  }
}

// Causal flash attention, swapped-QK^T in-register softmax.
// Block = (b,h, q-tile pair {p, 31-p}); 4 waves x 16 q-rows per fragment.
// qh,kh: [B,H,S,HD] bf16. vt: [B,H,HD,S] bf16. ao: [B,S,D] bf16.
__global__ __launch_bounds__(256, 4) void attn_kernel(
    const u16* __restrict__ qh, const u16* __restrict__ kh,
    const u16* __restrict__ vt, u16* __restrict__ ao)
{
  __shared__ u16 Ks[2][4096];   // [64 kv][64 hd], 16B-chunk XOR swizzled
  __shared__ u16 Vs[2][4096];   // [64 d ][64 kv], same swizzle
  __shared__ u16 Ps[4][1024];   // per-wave P [16 q][64 kv], 16B-slot XOR swizzle

  const int t = threadIdx.x, w = t >> 6, lane = t & 63;
  int bid = (int)blockIdx.x;
  bid = (bid & 7) * 128 + (bid >> 3);          // bijective XCD swizzle (1024 % 8 == 0)
  const int pr = bid & 15, bh = bid >> 4;
  const int tA = pr, tB = 31 - pr;             // paired q-tiles: (tA+1)+(tB+1)=33 units
  const int x = lane & 15, g = lane >> 4, g4 = g * 4;

  const u16* Kb = kh + (size_t)bh * Sn * HDn;
  const u16* Vb = vt + (size_t)bh * HDn * Sn;
  const u16* Qb = qh + (size_t)bh * Sn * HDn;

  const int qgA = tA * 64 + w * 16 + x;
  const int qgB = tB * 64 + w * 16 + x;

  bf16x8 qA[2], qB[2];
  qA[0] = *(const bf16x8*)(Qb + (size_t)qgA * HDn + g * 8);
  qA[1] = *(const bf16x8*)(Qb + (size_t)qgA * HDn + 32 + g * 8);
  qB[0] = *(const bf16x8*)(Qb + (size_t)qgB * HDn + g * 8);
  qB[1] = *(const bf16x8*)(Qb + (size_t)qgB * HDn + 32 + g * 8);

  float mA = -1e30f, lA = 0.f, mB = -1e30f, lB = 0.f;
  f32x4 oA[4] = {}, oB[4] = {};

  const int NT = tB + 1;

  auto stageKV = [&](int buf, int j0) {
    #pragma unroll
    for (int i = 0; i < 2; ++i) {
      const int c = i * 256 + t;
      const int row = c >> 3;
      const int off = (c & 7) ^ (row & 7);     // inverse-swizzled source
      gload16(Kb + (size_t)(j0 + row) * HDn + off * 8, &Ks[buf][(c & ~63) * 8]);
      gload16(Vb + (size_t)row * Sn + j0 + off * 8, &Vs[buf][(c & ~63) * 8]);
    }
  };

  // one (q-fragment x kv-tile) unit: S^T = mfma(K,Q) -> lane-local softmax ->
  // P packed through swizzled LDS -> O^T += mfma(V^T, P)
  auto unit = [&](const bf16x8* qf, float& m, float& l, f32x4* o,
                  int buf, int j, int tF, int qglob) {
    f32x4 st[4] = {};
    __builtin_amdgcn_s_setprio(1);
    #pragma unroll
    for (int ks = 0; ks < 2; ++ks)
      #pragma unroll
      for (int n = 0; n < 4; ++n) {
        const int row = n * 16 + x;
        const int ch = (ks * 4 + g) ^ (row & 7);
        bf16x8 kb = *(const bf16x8*)&Ks[buf][row * 64 + ch * 8];
        st[n] = __builtin_amdgcn_mfma_f32_16x16x32_bf16(kb, qf[ks], st[n], 0, 0, 0);
      }
    __builtin_amdgcn_s_setprio(0);

    const bool diag = (j == tF);
    const int kvb = j * 64 + g4;
    float mx = m;
    #pragma unroll
    for (int n = 0; n < 4; ++n)
      #pragma unroll
      for (int r = 0; r < 4; ++r) {
        float v = st[n][r] * 0.125f;                       // 1/sqrt(HD)
        if (diag && (kvb + n * 16 + r) > qglob) v -= 100000.0f;
        st[n][r] = v;
        mx = fmaxf(mx, v);
      }
    mx = fmaxf(mx, __shfl_xor(mx, 16, 64));
    mx = fmaxf(mx, __shfl_xor(mx, 32, 64));
    const float al = __expf(m - mx);
    m = mx;
    float s = 0.f;
    #pragma unroll
    for (int n = 0; n < 4; ++n)
      #pragma unroll
      for (int r = 0; r < 4; ++r) {
        const float e = __expf(st[n][r] - mx);
        st[n][r] = e;
        s += e;
      }
    s += __shfl_xor(s, 16, 64);
    s += __shfl_xor(s, 32, 64);
    l = l * al + s;
    #pragma unroll
    for (int n = 0; n < 4; ++n)
      #pragma unroll
      for (int r = 0; r < 4; ++r) o[n][r] *= al;

    // pack P (bf16) and write through per-wave swizzled LDS
    u16* pw = &Ps[w][x * 64];
    #pragma unroll
    for (int n = 0; n < 4; ++n) {
      u32 w0, w1;
      asm("v_cvt_pk_bf16_f32 %0, %1, %2" : "=v"(w0) : "v"(st[n][0]), "v"(st[n][1]));
      asm("v_cvt_pk_bf16_f32 %0, %1, %2" : "=v"(w1) : "v"(st[n][2]), "v"(st[n][3]));
      const int slot = (n * 2 + (g >> 1)) ^ (x & 7);
      uint2 val; val.x = w0; val.y = w1;
      *(uint2*)&pw[slot * 8 + (g & 1) * 4] = val;
    }
    asm volatile("s_waitcnt lgkmcnt(0)" ::: "memory");
    __builtin_amdgcn_sched_barrier(0);

    __builtin_amdgcn_s_setprio(1);
    #pragma unroll
    for (int ks = 0; ks < 2; ++ks) {
      bf16x8 pf = *(const bf16x8*)&pw[((ks * 4 + g) ^ (x & 7)) * 8];
      #pragma unroll
      for (int n = 0; n < 4; ++n) {
        const int row = n * 16 + x;
        const int ch = (ks * 4 + g) ^ (row & 7);
        bf16x8 vb = *(const bf16x8*)&Vs[buf][row * 64 + ch * 8];
        o[n] = __builtin_amdgcn_mfma_f32_16x16x32_bf16(vb, pf, o[n], 0, 0, 0);
      }
    }
    __builtin_amdgcn_s_setprio(0);
  };

  stageKV(0, 0);
  for (int j = 0; j < NT; ++j) {
    const int buf = j & 1;
    if (j + 1 < NT) stageKV(buf ^ 1, (j + 1) * 64);
    __syncthreads();
    unit(qB, mB, lB, oB, buf, j, tB, qgB);
    if (j <= tA) unit(qA, mA, lA, oA, buf, j, tA, qgA);
    __syncthreads();
  }

  const int b_ = bh >> 4, h_ = bh & 15;
  {
    const float rl = 1.0f / lA;
    u16* base = ao + ((size_t)b_ * Sn + qgA) * Dn + h_ * HDn;
    #pragma unroll
    for (int n = 0; n < 4; ++n) {
      ushort4 ov;
      ov.x = f2bf(oA[n][0] * rl); ov.y = f2bf(oA[n][1] * rl);
      ov.z = f2bf(oA[n][2] * rl); ov.w = f2bf(oA[n][3] * rl);
      *(ushort4*)&base[n * 16 + g4] = ov;
    }
  }
  {
    const float rl = 1.0f / lB;
    u16* base = ao + ((size_t)b_ * Sn + qgB) * Dn + h_ * HDn;
    #pragma unroll
    for (int n = 0; n < 4; ++n) {
      ushort4 ov;
      ov.x = f2bf(oB[n][0] * rl); ov.y = f2bf(oB[n][1] * rl);
      ov.z = f2bf(oB[n][2] * rl); ov.w = f2bf(oB[n][3] * rl);
      *(ushort4*)&base[n * 16 + g4] = ov;
    }
  }
}

extern "C" void kernel_launch(void* const* d_in, const int* in_sizes, int n_in,
                              void* d_out, int out_size, void* d_ws, size_t ws_size,
                              hipStream_t stream)
{
  const float* q  = (const float*)d_in[0];
  const float* k  = (const float*)d_in[1];
  const float* v  = (const float*)d_in[2];
  // d_in[3] = mask: fixed causal triu -> implemented analytically, never read
  const float* Wq = (const float*)d_in[4];
  const float* bq = (const float*)d_in[5];
  const float* Wk = (const float*)d_in[6];
  const float* bk = (const float*)d_in[7];
  const float* Wv = (const float*)d_in[8];
  const float* bv = (const float*)d_in[9];
  const float* Wo = (const float*)d_in[10];
  const float* bo = (const float*)d_in[11];

  float* out_o  = (float*)d_out;                       // [B,S,D]
  float* out_kh = out_o + (size_t)Bn * Sn * Dn;        // [B,H,S,HD]
  float* out_vh = out_kh + (size_t)Bn * Sn * Dn;       // [B,H,S,HD]

  char* ws = (char*)d_ws;
  const size_t MB = 1ull << 20;
  u16* wq_bf = (u16*)(ws + 0 * MB);
  u16* wk_bf = (u16*)(ws + 2 * MB);
  u16* wv_bf = (u16*)(ws + 4 * MB);
  u16* wo_bf = (u16*)(ws + 6 * MB);
  u16* q_bf  = (u16*)(ws + 8 * MB);     // [8192,1024] bf16
  u16* k_bf  = (u16*)(ws + 24 * MB);
  u16* v_bf  = (u16*)(ws + 40 * MB);
  u16* qh_bf = (u16*)(ws + 56 * MB);    // [B,H,S,HD]
  u16* kh_bf = (u16*)(ws + 72 * MB);    // [B,H,S,HD]
  u16* vt_bf = (u16*)(ws + 88 * MB);    // [B,H,HD,S]
  u16* ao_bf = q_bf;                    // alias: q_bf dead after GEMM Q

  const int NC = Bn * Sn * Dn / 4;      // 2,097,152 float4s
  cvt_kernel<<<NC / 256, 256, 0, stream>>>(q, q_bf, NC);
  cvt_kernel<<<NC / 256, 256, 0, stream>>>(k, k_bf, NC);
  cvt_kernel<<<NC / 256, 256, 0, stream>>>(v, v_bf, NC);
  const int NW = Dn * Dn / 4;           // 262,144
  cvt_kernel<<<NW / 256, 256, 0, stream>>>(Wq, wq_bf, NW);
  cvt_kernel<<<NW / 256, 256, 0, stream>>>(Wk, wk_bf, NW);
  cvt_kernel<<<NW / 256, 256, 0, stream>>>(Wv, wv_bf, NW);
  cvt_kernel<<<NW / 256, 256, 0, stream>>>(Wo, wo_bf, NW);

  gemm_bt<0><<<512, 256, 0, stream>>>(q_bf, wq_bf, bq, nullptr, qh_bf);
  gemm_bt<1><<<512, 256, 0, stream>>>(k_bf, wk_bf, bk, out_kh, kh_bf);
  gemm_bt<2><<<512, 256, 0, stream>>>(v_bf, wv_bf, bv, out_vh, vt_bf);

  attn_kernel<<<1024, 256, 0, stream>>>(qh_bf, kh_bf, vt_bf, ao_bf);

  gemm_bt<3><<<512, 256, 0, stream>>>(ao_bf, wo_bf, bo, out_o, nullptr);
}

// Round 4
// 223.423 us; speedup vs baseline: 1.4331x; 1.0995x over previous
//
#include <hip/hip_runtime.h>
#include <stdint.h>

#define Bn 4
#define Sn 2048
#define Dn 1024
#define Hn 16
#define HDn 64

typedef unsigned short u16;
typedef unsigned int u32;
typedef __attribute__((ext_vector_type(8))) __bf16 bf16x8;
typedef __attribute__((ext_vector_type(4))) float f32x4;
typedef __attribute__((ext_vector_type(16))) float f32x16;
typedef __attribute__((ext_vector_type(4))) u32 u32x4;

// 0.125 (1/sqrt(HD)) * log2(e): folded into Q projection -> QK^T lands in exp2 domain
#define CEXP 0.18033688011112042f

#define EXP2F(x) __builtin_amdgcn_exp2f(x)

__device__ __forceinline__ u16 f2bf(float f) {
  union { float f; u32 u; } x; x.f = f;
  u32 r = x.u + 0x7FFFu + ((x.u >> 16) & 1u);   // RNE
  return (u16)(r >> 16);
}

__device__ __forceinline__ void gload16(const u16* g, u16* l) {
  __builtin_amdgcn_global_load_lds(
      (const __attribute__((address_space(1))) void*)g,
      (__attribute__((address_space(3))) void*)l, 16, 0, 0);
}

__global__ void cvt_kernel(const float* __restrict__ in, u16* __restrict__ out, int n4) {
  int i = blockIdx.x * 256 + threadIdx.x;
  if (i < n4) {
    float4 v = ((const float4*)in)[i];
    ushort4 o;
    o.x = f2bf(v.x); o.y = f2bf(v.y); o.z = f2bf(v.z); o.w = f2bf(v.w);
    ((ushort4*)out)[i] = o;
  }
}

// C[M=8192, N=1024] = A[M,K=1024] @ W[N,K]^T + bias, bf16 inputs, fp32 accum.
// Single barrier per K-step; stage issued after barrier so loads overlap MFMA.
template<int MODE>
__global__ __launch_bounds__(256, 2) void gemm_bt(
    const u16* __restrict__ A, const u16* __restrict__ W,
    const float* __restrict__ bias,
    float* __restrict__ outF, u16* __restrict__ outB)
{
  __shared__ u16 As[2][4096];  // [128][32] bf16, chunk-XOR swizzled
  __shared__ u16 Bs[2][4096];

  const int t = threadIdx.x, w = t >> 6, lane = t & 63;
  int bid = (int)blockIdx.x;
  bid = (bid & 7) * 64 + (bid >> 3);          // bijective XCD swizzle (512 % 8 == 0)
  const int m0 = (bid >> 3) * 128, n0 = (bid & 7) * 128;
  const int wm = (w >> 1) * 64, wn = (w & 1) * 64;
  const int lrow = lane & 15;

  f32x4 acc[4][4] = {};

  auto stage = [&](int buf, int k0) {
    #pragma unroll
    for (int i = 0; i < 2; ++i) {
      const int c = i * 256 + t;
      const int row = c >> 2;
      const int off = ((c & 3) ^ (row & 3)) * 8;   // inverse-swizzled source
      gload16(A + (size_t)(m0 + row) * 1024 + k0 + off, &As[buf][(c & ~63) * 8]);
      gload16(W + (size_t)(n0 + row) * 1024 + k0 + off, &Bs[buf][(c & ~63) * 8]);
    }
  };

  stage(0, 0);
  for (int kt = 0; kt < 32; ++kt) {
    const int buf = kt & 1;
    __syncthreads();                          // drains stage of buf; one barrier/iter
    if (kt < 31) stage(buf ^ 1, (kt + 1) * 32);  // flies over the MFMAs below
    bf16x8 a[4], b[4];
    #pragma unroll
    for (int i = 0; i < 4; ++i) {
      const int ra = wm + i * 16 + lrow;
      const int rb = wn + i * 16 + lrow;
      a[i] = *(const bf16x8*)&As[buf][ra * 32 + (((lane >> 4) ^ (ra & 3)) * 8)];
      b[i] = *(const bf16x8*)&Bs[buf][rb * 32 + (((lane >> 4) ^ (rb & 3)) * 8)];
    }
    #pragma unroll
    for (int i = 0; i < 4; ++i)
      #pragma unroll
      for (int j = 0; j < 4; ++j)
        acc[i][j] = __builtin_amdgcn_mfma_f32_16x16x32_bf16(a[i], b[j], acc[i][j], 0, 0, 0);
  }

  const int g4 = (lane >> 4) * 4;
  #pragma unroll
  for (int i = 0; i < 4; ++i) {
    #pragma unroll
    for (int j = 0; j < 4; ++j) {
      const int gn = n0 + wn + j * 16 + lrow;
      const float bv = bias[gn];
      #pragma unroll
      for (int r = 0; r < 4; ++r) {
        const int gm = m0 + wm + i * 16 + g4 + r;
        const float x = acc[i][j][r] + bv;
        if (MODE == 3) {
          outF[(size_t)gm * 1024 + gn] = x;
        } else {
          const int b_ = gm >> 11, s_ = gm & 2047, h_ = gn >> 6, d_ = gn & 63;
          const size_t hidx = (((size_t)b_ * Hn + h_) * Sn + s_) * HDn + d_;
          if (MODE == 0) outB[hidx] = f2bf(x * CEXP);  // exp2-domain prescale
          if (MODE == 1) { outF[hidx] = x; outB[hidx] = f2bf(x); }
          if (MODE == 2) { outF[hidx] = x;
                           outB[(((size_t)b_ * Hn + h_) * HDn + d_) * Sn + s_] = f2bf(x); }
        }
      }
    }
  }
}

// Causal flash attention: 32x32 MFMA, Q in registers, in-register softmax +
// permlane32_swap P redistribution (no P LDS). Block = 4 waves x 32q = 128 q-rows,
// paired q-tiles (p, 15-p) for balance. qh is pre-scaled by CEXP.
__global__ __launch_bounds__(256, 2) void attn_kernel(
    const u16* __restrict__ qh, const u16* __restrict__ kh,
    const u16* __restrict__ vt, u16* __restrict__ ao)
{
  __shared__ u16 Ks[2][4096];   // [64 kv][64 hd], 16B-chunk XOR(row&7) swizzled
  __shared__ u16 Vs[2][4096];   // [64 d ][64 kv], same swizzle

  const int t = threadIdx.x, w = t >> 6, lane = t & 63;
  int bid = (int)blockIdx.x;
  bid = (bid & 7) * 64 + (bid >> 3);           // bijective XCD swizzle (512 % 8 == 0)
  const int pr = bid & 7, bh = bid >> 3;
  const int l31 = lane & 31, h = lane >> 5;
  const int cxor = l31 & 7;                    // row&7 for all our LDS rows

  const u16* Kb = kh + (size_t)bh * Sn * HDn;
  const u16* Vb = vt + (size_t)bh * HDn * Sn;
  const u16* Qb = qh + (size_t)bh * Sn * HDn;

  const int q0A = pr * 128 + w * 32;           // tile A = pr (small)
  const int q0B = (15 - pr) * 128 + w * 32;    // tile B = 15-pr (large)
  const int qA = q0A + l31, qB = q0B + l31;

  // Q fragments in registers: lane holds Q[q][kk*16 + h*8 .. +7]
  bf16x8 qfA[4], qfB[4];
  #pragma unroll
  for (int kk = 0; kk < 4; ++kk) {
    qfA[kk] = *(const bf16x8*)(Qb + (size_t)qA * HDn + kk * 16 + h * 8);
    qfB[kk] = *(const bf16x8*)(Qb + (size_t)qB * HDn + kk * 16 + h * 8);
  }

  float mA = -1e30f, lA = 0.f, mB = -1e30f, lB = 0.f;
  f32x16 oA0 = {}, oA1 = {}, oB0 = {}, oB1 = {};

  const int NT = 2 * (16 - pr);
  const int jAmax = (q0A + 31) >> 6, jBmax = (q0B + 31) >> 6;

  auto stageKV = [&](int buf, int j0) {
    #pragma unroll
    for (int i = 0; i < 2; ++i) {
      const int c = i * 256 + t;
      const int row = c >> 3;
      const int off = (c & 7) ^ (row & 7);     // inverse-swizzled source
      gload16(Kb + (size_t)(j0 + row) * HDn + off * 8, &Ks[buf][(c & ~63) * 8]);
      gload16(Vb + (size_t)row * Sn + j0 + off * 8, &Vs[buf][(c & ~63) * 8]);
    }
  };

  auto unit = [&](const bf16x8* qf, float& m, float& l, f32x16& o0, f32x16& o1,
                  int buf, int jt, int q0w, int qg) {
    const u16* Kbuf = &Ks[buf][0];
    const u16* Vbuf = &Vs[buf][0];
    f32x16 s0 = {}, s1 = {};

    // S^T[kv][q] = K · Q^T   (8 mfma, A=K from LDS, B=Q from regs)
    __builtin_amdgcn_s_setprio(1);
    #pragma unroll
    for (int kk = 0; kk < 4; ++kk) {
      const int ch = ((kk * 2 + h) ^ cxor) * 8;
      bf16x8 k0 = *(const bf16x8*)&Kbuf[l31 * 64 + ch];
      bf16x8 k1 = *(const bf16x8*)&Kbuf[(32 + l31) * 64 + ch];
      s0 = __builtin_amdgcn_mfma_f32_32x32x16_bf16(k0, qf[kk], s0, 0, 0, 0);
      s1 = __builtin_amdgcn_mfma_f32_32x32x16_bf16(k1, qf[kk], s1, 0, 0, 0);
    }
    __builtin_amdgcn_s_setprio(0);

    // causal mask (exp2 domain): kv = jt*64 + tsub*32 + (r&3)+8*(r>>2)+4h
    if (jt * 64 + 63 > q0w) {
      const int kvb = jt * 64 + 4 * h;
      #pragma unroll
      for (int r = 0; r < 16; ++r) {
        const int rho = (r & 3) + 8 * (r >> 2);
        s0[r] = (kvb + rho > qg) ? -1e30f : s0[r];
        s1[r] = (kvb + 32 + rho > qg) ? -1e30f : s1[r];
      }
    }

    // row max (lane-local 32 + cross-half)
    float mx = s0[0];
    #pragma unroll
    for (int r = 1; r < 16; ++r) mx = fmaxf(mx, s0[r]);
    #pragma unroll
    for (int r = 0; r < 16; ++r) mx = fmaxf(mx, s1[r]);
    mx = fmaxf(mx, __shfl_xor(mx, 32, 64));

    // defer-max: rescale only when max grows past 8/ln2
    if (__any(mx > m + 11.5415603f)) {
      const float mn = fmaxf(m, mx);
      const float al = EXP2F(m - mn);
      m = mn; l *= al;
      #pragma unroll
      for (int r = 0; r < 16; ++r) { o0[r] *= al; o1[r] *= al; }
    }

    float sum = 0.f;
    #pragma unroll
    for (int r = 0; r < 16; ++r) { s0[r] = EXP2F(s0[r] - m); sum += s0[r]; }
    #pragma unroll
    for (int r = 0; r < 16; ++r) { s1[r] = EXP2F(s1[r] - m); sum += s1[r]; }
    sum += __shfl_xor(sum, 32, 64);
    l += sum;

    // P -> bf16 words; in-register redistribution via permlane32_swap.
    u32 w0[8], w1[8];
    #pragma unroll
    for (int i = 0; i < 8; ++i) {
      asm("v_cvt_pk_bf16_f32 %0, %1, %2" : "=v"(w0[i]) : "v"(s0[2 * i]), "v"(s0[2 * i + 1]));
      asm("v_cvt_pk_bf16_f32 %0, %1, %2" : "=v"(w1[i]) : "v"(s1[2 * i]), "v"(s1[2 * i + 1]));
    }
    asm("v_permlane32_swap_b32 %0, %1" : "+v"(w0[0]), "+v"(w0[2]));
    asm("v_permlane32_swap_b32 %0, %1" : "+v"(w0[1]), "+v"(w0[3]));
    asm("v_permlane32_swap_b32 %0, %1" : "+v"(w0[4]), "+v"(w0[6]));
    asm("v_permlane32_swap_b32 %0, %1" : "+v"(w0[5]), "+v"(w0[7]));
    asm("v_permlane32_swap_b32 %0, %1" : "+v"(w1[0]), "+v"(w1[2]));
    asm("v_permlane32_swap_b32 %0, %1" : "+v"(w1[1]), "+v"(w1[3]));
    asm("v_permlane32_swap_b32 %0, %1" : "+v"(w1[4]), "+v"(w1[6]));
    asm("v_permlane32_swap_b32 %0, %1" : "+v"(w1[5]), "+v"(w1[7]));

    // O^T += V^T · P^T  (A=V^T from LDS chunk c=2s+h, B=P from regs)
    __builtin_amdgcn_s_setprio(1);
    #pragma unroll
    for (int s = 0; s < 4; ++s) {
      const u32* wt = (s < 2) ? w0 : w1;
      const int j4 = (s & 1) * 4;
      u32x4 fr = { wt[j4], wt[j4 + 1], wt[j4 + 2], wt[j4 + 3] };
      bf16x8 pf = __builtin_bit_cast(bf16x8, fr);
      const int ch = ((2 * s + h) ^ cxor) * 8;
      bf16x8 v0 = *(const bf16x8*)&Vbuf[l31 * 64 + ch];
      bf16x8 v1 = *(const bf16x8*)&Vbuf[(32 + l31) * 64 + ch];
      o0 = __builtin_amdgcn_mfma_f32_32x32x16_bf16(v0, pf, o0, 0, 0, 0);
      o1 = __builtin_amdgcn_mfma_f32_32x32x16_bf16(v1, pf, o1, 0, 0, 0);
    }
    __builtin_amdgcn_s_setprio(0);
  };

  stageKV(0, 0);
  for (int jt = 0; jt < NT; ++jt) {
    const int buf = jt & 1;
    __syncthreads();                          // drains stage of buf
    if (jt + 1 < NT) stageKV(buf ^ 1, (jt + 1) * 64);  // overlaps compute
    if (jt <= jBmax) unit(qfB, mB, lB, oB0, oB1, buf, jt, q0B, qB);
    if (jt <= jAmax) unit(qfA, mA, lA, oA0, oA1, buf, jt, q0A, qA);
  }

  const int b_ = bh >> 4, h_ = bh & 15;
  {
    const float rl = 1.0f / lA;
    u16* base = ao + ((size_t)b_ * Sn + qA) * Dn + h_ * HDn;
    #pragma unroll
    for (int n = 0; n < 2; ++n)
      #pragma unroll
      for (int u = 0; u < 4; ++u) {
        const f32x16& o = n ? oA1 : oA0;
        ushort4 ov;
        ov.x = f2bf(o[4 * u + 0] * rl); ov.y = f2bf(o[4 * u + 1] * rl);
        ov.z = f2bf(o[4 * u + 2] * rl); ov.w = f2bf(o[4 * u + 3] * rl);
        *(ushort4*)&base[n * 32 + 8 * u + 4 * h] = ov;
      }
  }
  {
    const float rl = 1.0f / lB;
    u16* base = ao + ((size_t)b_ * Sn + qB) * Dn + h_ * HDn;
    #pragma unroll
    for (int n = 0; n < 2; ++n)
      #pragma unroll
      for (int u = 0; u < 4; ++u) {
        const f32x16& o = n ? oB1 : oB0;
        ushort4 ov;
        ov.x = f2bf(o[4 * u + 0] * rl); ov.y = f2bf(o[4 * u + 1] * rl);
        ov.z = f2bf(o[4 * u + 2] * rl); ov.w = f2bf(o[4 * u + 3] * rl);
        *(ushort4*)&base[n * 32 + 8 * u + 4 * h] = ov;
      }
  }
}

extern "C" void kernel_launch(void* const* d_in, const int* in_sizes, int n_in,
                              void* d_out, int out_size, void* d_ws, size_t ws_size,
                              hipStream_t stream)
{
  const float* q  = (const float*)d_in[0];
  const float* k  = (const float*)d_in[1];
  const float* v  = (const float*)d_in[2];
  // d_in[3] = mask: fixed causal triu -> implemented analytically, never read
  const float* Wq = (const float*)d_in[4];
  const float* bq = (const float*)d_in[5];
  const float* Wk = (const float*)d_in[6];
  const float* bk = (const float*)d_in[7];
  const float* Wv = (const float*)d_in[8];
  const float* bv = (const float*)d_in[9];
  const float* Wo = (const float*)d_in[10];
  const float* bo = (const float*)d_in[11];

  float* out_o  = (float*)d_out;                       // [B,S,D]
  float* out_kh = out_o + (size_t)Bn * Sn * Dn;        // [B,H,S,HD]
  float* out_vh = out_kh + (size_t)Bn * Sn * Dn;       // [B,H,S,HD]

  char* ws = (char*)d_ws;
  const size_t MB = 1ull << 20;
  u16* wq_bf = (u16*)(ws + 0 * MB);
  u16* wk_bf = (u16*)(ws + 2 * MB);
  u16* wv_bf = (u16*)(ws + 4 * MB);
  u16* wo_bf = (u16*)(ws + 6 * MB);
  u16* q_bf  = (u16*)(ws + 8 * MB);     // [8192,1024] bf16
  u16* k_bf  = (u16*)(ws + 24 * MB);
  u16* v_bf  = (u16*)(ws + 40 * MB);
  u16* qh_bf = (u16*)(ws + 56 * MB);    // [B,H,S,HD] (CEXP-prescaled)
  u16* kh_bf = (u16*)(ws + 72 * MB);    // [B,H,S,HD]
  u16* vt_bf = (u16*)(ws + 88 * MB);    // [B,H,HD,S]
  u16* ao_bf = q_bf;                    // alias: q_bf dead after GEMM Q

  const int NC = Bn * Sn * Dn / 4;      // 2,097,152 float4s
  cvt_kernel<<<NC / 256, 256, 0, stream>>>(q, q_bf, NC);
  cvt_kernel<<<NC / 256, 256, 0, stream>>>(k, k_bf, NC);
  cvt_kernel<<<NC / 256, 256, 0, stream>>>(v, v_bf, NC);
  const int NW = Dn * Dn / 4;           // 262,144
  cvt_kernel<<<NW / 256, 256, 0, stream>>>(Wq, wq_bf, NW);
  cvt_kernel<<<NW / 256, 256, 0, stream>>>(Wk, wk_bf, NW);
  cvt_kernel<<<NW / 256, 256, 0, stream>>>(Wv, wv_bf, NW);
  cvt_kernel<<<NW / 256, 256, 0, stream>>>(Wo, wo_bf, NW);

  gemm_bt<0><<<512, 256, 0, stream>>>(q_bf, wq_bf, bq, nullptr, qh_bf);
  gemm_bt<1><<<512, 256, 0, stream>>>(k_bf, wk_bf, bk, out_kh, kh_bf);
  gemm_bt<2><<<512, 256, 0, stream>>>(v_bf, wv_bf, bv, out_vh, vt_bf);

  attn_kernel<<<512, 256, 0, stream>>>(qh_bf, kh_bf, vt_bf, ao_bf);

  gemm_bt<3><<<512, 256, 0, stream>>>(ao_bf, wo_bf, bo, out_o, nullptr);
}